// Round 1
// baseline (491.831 us; speedup 1.0000x reference)
//
#include <hip/hip_runtime.h>
#include <math.h>

#define BATCH    4096
#define SEQ_T    512
#define ISZ      4
#define HID      64
#define OSZ      40

// fast tanh: tanh(x) = sign(x) * (1 - e)/(1 + e), e = exp(-2|x|)
__device__ __forceinline__ float fast_tanh(float x) {
    float ax = fabsf(x);
    float e  = __expf(-2.0f * ax);                       // v_mul + v_exp
    float r  = (1.0f - e) * __builtin_amdgcn_rcpf(1.0f + e);
    return copysignf(r, x);
}

// One wave (64 lanes) owns one batch element for all T steps.
// lane = hidden index h'. W_hh row h' lives in 64 VGPRs per lane.
// h vector lives in LDS; recurrent dot uses lane-uniform float4 broadcasts.
__global__ __launch_bounds__(256, 4)
void rnn_fp32_kernel(const float* __restrict__ x,
                     const float* __restrict__ W_ih,
                     const float* __restrict__ W_hh,
                     const float* __restrict__ b_ih,
                     const float* __restrict__ b_hh,
                     const float* __restrict__ fc_W,
                     const float* __restrict__ fc_b,
                     float* __restrict__ out)
{
    __shared__ float h_sh[4][HID];          // per-wave hidden state
    __shared__ float fcwT[HID][OSZ];        // fc_W transposed: [j][o]

    const int tid  = threadIdx.x;
    const int wave = tid >> 6;
    const int lane = tid & 63;
    const int b    = blockIdx.x * 4 + wave;

    // Stage fc_W transposed into LDS (coalesced read, once per block)
    for (int idx = tid; idx < OSZ * HID; idx += 256) {
        const int o = idx >> 6;             // row of fc_W
        const int j = idx & 63;             // col of fc_W
        fcwT[j][o] = fc_W[idx];
    }
    __syncthreads();

    // Per-lane recurrent weight row W_hh[lane][0..63] -> registers
    float w[HID];
    #pragma unroll
    for (int k = 0; k < HID / 4; ++k) {
        const float4 v = *reinterpret_cast<const float4*>(W_hh + lane * HID + k * 4);
        w[4*k+0] = v.x; w[4*k+1] = v.y; w[4*k+2] = v.z; w[4*k+3] = v.w;
    }
    const float4 wi  = *reinterpret_cast<const float4*>(W_ih + lane * ISZ);
    const float bias = b_ih[lane] + b_hh[lane];

    const float* xb = x + (size_t)b * SEQ_T * ISZ;
    float4 xv = *reinterpret_cast<const float4*>(xb);   // x[b][0][:]
    float hval = 0.0f;                                  // h0 = 0

    for (int t = 0; t < SEQ_T; ++t) {
        // publish current h to LDS (stride-1 across lanes: conflict-free)
        h_sh[wave][lane] = hval;

        // prefetch next timestep's input (clamped to stay in bounds)
        const int tn = (t + 1 < SEQ_T) ? (t + 1) : (SEQ_T - 1);
        const float4 xn = *reinterpret_cast<const float4*>(xb + tn * ISZ);

        // input projection + bias
        float a0 = fmaf(xv.x, wi.x, bias);
        a0 = fmaf(xv.y, wi.y, a0);
        a0 = fmaf(xv.z, wi.z, a0);
        a0 = fmaf(xv.w, wi.w, a0);
        float a1 = 0.0f, a2 = 0.0f, a3 = 0.0f;

        // recurrent dot: 16 lane-uniform b128 broadcasts, 64 fmacs,
        // 4 independent accumulator chains
        #pragma unroll
        for (int j4 = 0; j4 < HID / 4; ++j4) {
            const float4 hv = *reinterpret_cast<const float4*>(&h_sh[wave][j4 * 4]);
            a0 = fmaf(hv.x, w[4*j4+0], a0);
            a1 = fmaf(hv.y, w[4*j4+1], a1);
            a2 = fmaf(hv.z, w[4*j4+2], a2);
            a3 = fmaf(hv.w, w[4*j4+3], a3);
        }

        hval = fast_tanh((a0 + a1) + (a2 + a3));
        xv = xn;
    }

    // publish final hidden state
    h_sh[wave][lane] = hval;

    // fc epilogue: lanes 0..39 each compute one output feature
    if (lane < OSZ) {
        float acc = fc_b[lane];
        #pragma unroll
        for (int j = 0; j < HID; ++j)
            acc = fmaf(h_sh[wave][j], fcwT[j][lane], acc);
        out[b * OSZ + lane] = acc;
    }
}

extern "C" void kernel_launch(void* const* d_in, const int* in_sizes, int n_in,
                              void* d_out, int out_size, void* d_ws, size_t ws_size,
                              hipStream_t stream) {
    const float* x    = (const float*)d_in[0];
    const float* W_ih = (const float*)d_in[1];
    const float* W_hh = (const float*)d_in[2];
    const float* b_ih = (const float*)d_in[3];
    const float* b_hh = (const float*)d_in[4];
    const float* fc_W = (const float*)d_in[5];
    const float* fc_b = (const float*)d_in[6];
    float* out = (float*)d_out;

    rnn_fp32_kernel<<<BATCH / 4, 256, 0, stream>>>(
        x, W_ih, W_hh, b_ih, b_hh, fc_W, fc_b, out);
}

// Round 3
// 405.364 us; speedup vs baseline: 1.2133x; 1.2133x over previous
//
#include <hip/hip_runtime.h>
#include <math.h>

#define BATCH 4096
#define SEQ_T 512
#define ISZ   4
#define HID   64
#define OSZ   40
#define RPB   8      // valid batch per block (MFMA N=16 cols, 8 used -> 512 blocks, 2/CU)
#define RSTR  200    // shorts per LDS row: 3 terms x 64 + 8 pad (bank start = 4n%32)

typedef __attribute__((ext_vector_type(8))) short  short8;
typedef __attribute__((ext_vector_type(4))) short  short4v;
typedef __attribute__((ext_vector_type(4))) float  float4v;

static __device__ __forceinline__ unsigned short f2bf(float f) {
    unsigned int u = __builtin_bit_cast(unsigned int, f);
    u += 0x7FFFu + ((u >> 16) & 1u);          // RNE
    return (unsigned short)(u >> 16);
}
static __device__ __forceinline__ float bf2f(unsigned short s) {
    unsigned int u = ((unsigned int)s) << 16;
    return __builtin_bit_cast(float, u);
}
// tanh(x) = 1 - 2/(exp(2x)+1); saturates to +/-1, NaN-free
static __device__ __forceinline__ float fast_tanh(float x) {
    float e = __expf(2.0f * x);
    return 1.0f - 2.0f * __builtin_amdgcn_rcpf(e + 1.0f);
}

__global__ __launch_bounds__(256, 2)
void rnn_mfma3_kernel(const float* __restrict__ x,
                      const float* __restrict__ W_ih,
                      const float* __restrict__ W_hh,
                      const float* __restrict__ b_ih,
                      const float* __restrict__ b_hh,
                      const float* __restrict__ fc_W,
                      const float* __restrict__ fc_b,
                      float* __restrict__ out)
{
    // hx row n (batch): [h1 0..63 | h2 0..63 | h3 0..63 | pad]
    __shared__ __attribute__((aligned(16))) unsigned short hx[2][16][RSTR];
    __shared__ __attribute__((aligned(16))) float hf[16][68];   // final h fp32

    const int tid  = threadIdx.x;
    const int wave = tid >> 6;
    const int lane = tid & 63;
    const int n    = lane & 15;   // A-frag: row m; C/D + B-frag: col n (batch)
    const int q    = lane >> 4;
    const int blk0 = blockIdx.x * RPB;

    // h(0) = 0: zero both buffers (pads included, stay 0 forever)
    for (int i = tid; i < 2 * 16 * RSTR; i += 256)
        ((unsigned short*)hx)[i] = 0;

    // ---- static A fragments: W_hh rows 16*wave + m, 3-term bf16 split ----
    short8 whi0, whi1, wmd0, wmd1, wlo0, wlo1;
    {
        const float* wr = W_hh + (16 * wave + n) * HID;
        #pragma unroll
        for (int j = 0; j < 8; ++j) {
            {   // K-chunk 0: k = 8q + j
                float f  = wr[8 * q + j];
                unsigned short hi = f2bf(f);
                float r1 = f - bf2f(hi);
                unsigned short md = f2bf(r1);
                float r2 = r1 - bf2f(md);
                ((unsigned short*)&whi0)[j] = hi;
                ((unsigned short*)&wmd0)[j] = md;
                ((unsigned short*)&wlo0)[j] = f2bf(r2);
            }
            {   // K-chunk 1: k = 32 + 8q + j
                float f  = wr[32 + 8 * q + j];
                unsigned short hi = f2bf(f);
                float r1 = f - bf2f(hi);
                unsigned short md = f2bf(r1);
                float r2 = r1 - bf2f(md);
                ((unsigned short*)&whi1)[j] = hi;
                ((unsigned short*)&wmd1)[j] = md;
                ((unsigned short*)&wlo1)[j] = f2bf(r2);
            }
        }
    }

    // ---- fp32 x-projection weights + bias for C rows 16*wave + 4q + r ----
    const int r0 = 16 * wave + 4 * q;
    float wih[4][4], bias[4];
    #pragma unroll
    for (int r = 0; r < 4; ++r) {
        bias[r] = b_ih[r0 + r] + b_hh[r0 + r];
        #pragma unroll
        for (int i = 0; i < ISZ; ++i) wih[r][i] = W_ih[(r0 + r) * ISZ + i];
    }

    // ---- per-lane x pipeline (fp32, straight from global; pads mirror n&7) ----
    const float* xrow = x + (size_t)(blk0 + (n & 7)) * SEQ_T * ISZ;
    float4v xcur = *(const float4v*)(xrow);
    float4v xnxt = *(const float4v*)(xrow + ISZ);

    float hl0 = 0.f, hl1 = 0.f, hl2 = 0.f, hl3 = 0.f;  // last fp32 h (for fc)

    __syncthreads();   // zero-init visible

#define MFMA(A, B, C) __builtin_amdgcn_mfma_f32_16x16x32_bf16((A), (B), (C), 0, 0, 0)
#define RNN_STEP(RB, WB, T)                                                   \
    {                                                                         \
        int tn = (T) + 2; if (tn > SEQ_T - 1) tn = SEQ_T - 1;                 \
        const float4v xf = *(const float4v*)(xrow + tn * ISZ);                \
        const unsigned short* rrow = &hx[RB][n][0];                           \
        short8 b00 = *(const short8*)(rrow +   0 + 8 * q);                    \
        short8 b01 = *(const short8*)(rrow +  32 + 8 * q);                    \
        short8 b10 = *(const short8*)(rrow +  64 + 8 * q);                    \
        short8 b11 = *(const short8*)(rrow +  96 + 8 * q);                    \
        short8 b20 = *(const short8*)(rrow + 128 + 8 * q);                    \
        short8 b21 = *(const short8*)(rrow + 160 + 8 * q);                    \
        float4v a0 = {0.f, 0.f, 0.f, 0.f}, a1 = {0.f, 0.f, 0.f, 0.f};         \
        a0 = MFMA(whi0, b00, a0);  a1 = MFMA(whi1, b01, a1);                  \
        a0 = MFMA(wmd0, b00, a0);  a1 = MFMA(wmd1, b01, a1);                  \
        a0 = MFMA(wlo0, b00, a0);  a1 = MFMA(wlo1, b01, a1);                  \
        a0 = MFMA(whi0, b10, a0);  a1 = MFMA(whi1, b11, a1);                  \
        a0 = MFMA(wmd0, b10, a0);  a1 = MFMA(wmd1, b11, a1);                  \
        a0 = MFMA(whi0, b20, a0);  a1 = MFMA(whi1, b21, a1);                  \
        float p0 = bias[0], p1 = bias[1], p2 = bias[2], p3 = bias[3];         \
        _Pragma("unroll")                                                     \
        for (int i = 0; i < ISZ; ++i) {                                       \
            p0 = fmaf(xcur[i], wih[0][i], p0);                                \
            p1 = fmaf(xcur[i], wih[1][i], p1);                                \
            p2 = fmaf(xcur[i], wih[2][i], p2);                                \
            p3 = fmaf(xcur[i], wih[3][i], p3);                                \
        }                                                                     \
        hl0 = fast_tanh(p0 + (a0[0] + a1[0]));                                \
        hl1 = fast_tanh(p1 + (a0[1] + a1[1]));                                \
        hl2 = fast_tanh(p2 + (a0[2] + a1[2]));                                \
        hl3 = fast_tanh(p3 + (a0[3] + a1[3]));                                \
        short4v t0, t1, t2;                                                   \
        {                                                                     \
            float v, rr; unsigned short s;                                    \
            v = hl0; s = f2bf(v); t0[0] = (short)s; rr = v - bf2f(s);         \
            s = f2bf(rr); t1[0] = (short)s; rr -= bf2f(s); t2[0] = (short)f2bf(rr); \
            v = hl1; s = f2bf(v); t0[1] = (short)s; rr = v - bf2f(s);         \
            s = f2bf(rr); t1[1] = (short)s; rr -= bf2f(s); t2[1] = (short)f2bf(rr); \
            v = hl2; s = f2bf(v); t0[2] = (short)s; rr = v - bf2f(s);         \
            s = f2bf(rr); t1[2] = (short)s; rr -= bf2f(s); t2[2] = (short)f2bf(rr); \
            v = hl3; s = f2bf(v); t0[3] = (short)s; rr = v - bf2f(s);         \
            s = f2bf(rr); t1[3] = (short)s; rr -= bf2f(s); t2[3] = (short)f2bf(rr); \
        }                                                                     \
        unsigned short* wrow = &hx[WB][n][0];                                 \
        const int fo = 16 * wave + 4 * q;                                     \
        *(short4v*)(wrow +   0 + fo) = t0;                                    \
        *(short4v*)(wrow +  64 + fo) = t1;                                    \
        *(short4v*)(wrow + 128 + fo) = t2;                                    \
        xcur = xnxt; xnxt = xf;                                               \
        __syncthreads();                                                      \
    }

    for (int t = 0; t < SEQ_T; t += 2) {
        RNN_STEP(0, 1, t)
        RNN_STEP(1, 0, t + 1)
    }
#undef RNN_STEP
#undef MFMA

    // ---- fc epilogue on fp32 final h ----
    {
        float4v hv = {hl0, hl1, hl2, hl3};
        *(float4v*)&hf[n][16 * wave + 4 * q] = hv;
    }
    __syncthreads();
    for (int it = tid; it < RPB * OSZ; it += 256) {
        const int b = it / OSZ;
        const int o = it - b * OSZ;
        const float* wo = fc_W + o * HID;
        float acc = fc_b[o];
        #pragma unroll
        for (int j = 0; j < HID; ++j)
            acc = fmaf(hf[b][j], wo[j], acc);
        out[(size_t)(blk0 + b) * OSZ + o] = acc;
    }
}

extern "C" void kernel_launch(void* const* d_in, const int* in_sizes, int n_in,
                              void* d_out, int out_size, void* d_ws, size_t ws_size,
                              hipStream_t stream) {
    const float* x    = (const float*)d_in[0];
    const float* W_ih = (const float*)d_in[1];
    const float* W_hh = (const float*)d_in[2];
    const float* b_ih = (const float*)d_in[3];
    const float* b_hh = (const float*)d_in[4];
    const float* fc_W = (const float*)d_in[5];
    const float* fc_b = (const float*)d_in[6];
    float* out = (float*)d_out;

    rnn_mfma3_kernel<<<BATCH / RPB, 256, 0, stream>>>(
        x, W_ih, W_hh, b_ih, b_hh, fc_W, fc_b, out);
}

// Round 5
// 230.832 us; speedup vs baseline: 2.1307x; 1.7561x over previous
//
#include <hip/hip_runtime.h>
#include <math.h>

#define BATCH 4096
#define SEQ_T 512
#define ISZ   4
#define HID   64
#define OSZ   40
#define RPB   16     // full MFMA N: 16 batch rows per block, 256 blocks = 1/CU

typedef __attribute__((ext_vector_type(8))) _Float16     half8;
typedef __attribute__((ext_vector_type(2))) _Float16     half2v;
typedef __attribute__((ext_vector_type(4))) float        float4v;
typedef __attribute__((ext_vector_type(2))) unsigned int uint2v;

static __device__ __forceinline__ half2v pk_f16(float a, float b) {
    return __builtin_bit_cast(half2v, __builtin_amdgcn_cvt_pkrtz(a, b)); // v_cvt_pkrtz_f16_f32
}

// tanh(x) = 1 - 2/(exp(2x)+1); saturates to +/-1, NaN-free
static __device__ __forceinline__ float fast_tanh(float x) {
    float e = __expf(2.0f * x);
    return 1.0f - 2.0f * __builtin_amdgcn_rcpf(e + 1.0f);
}

__global__ __launch_bounds__(256, 1)
void rnn_f16x2_kernel(const float* __restrict__ x,
                      const float* __restrict__ W_ih,
                      const float* __restrict__ W_hh,
                      const float* __restrict__ b_ih,
                      const float* __restrict__ b_hh,
                      const float* __restrict__ fc_W,
                      const float* __restrict__ fc_b,
                      float* __restrict__ out)
{
    // h terms in B-fragment-native order: hterm[buf][tau][g][n][j] = h_tau[k=8g+j] for batch col n.
    // Reader lane(n,q): b128 at [tau][4c+q][n][0] -> banks (4n+d)%32, 2-way (free, m136).
    // Writer lane(n,q) wave w: rows 16w+4q+r -> g=2w+(q>>1), j0=4(q&1): one b64 per term, 2-way.
    __shared__ __attribute__((aligned(16))) _Float16 hterm[2][2][8][16][8];
    __shared__ __attribute__((aligned(16))) float hf[16][68];

    const int tid  = threadIdx.x;
    const int wv   = tid >> 6;
    const int lane = tid & 63;
    const int n    = lane & 15;    // A: row m; B/C/D: batch col n
    const int q    = lane >> 4;
    const int blk0 = blockIdx.x * RPB;

    // h(0) = 0: zero both buffers
    {
        unsigned int* p = (unsigned int*)hterm;
        #pragma unroll
        for (int i = tid; i < (int)(sizeof(hterm) / 4); i += 256) p[i] = 0u;
    }

    // ---- static A fragments: W_hh row 16wv+n, 2-term fp16 split, K-chunks c=0,1 ----
    half8 A10, A11, A20, A21;   // A1x = hi term, A2x = residual term
    {
        const float* wr = W_hh + (16 * wv + n) * HID;
        #pragma unroll
        for (int j = 0; j < 8; ++j) {
            float f0 = wr[     8 * q + j];
            float f1 = wr[32 + 8 * q + j];
            _Float16 h0 = (_Float16)f0; A10[j] = h0; A20[j] = (_Float16)(f0 - (float)h0);
            _Float16 h1 = (_Float16)f1; A11[j] = h1; A21[j] = (_Float16)(f1 - (float)h1);
        }
    }

    // ---- fp32 x-projection weights + bias for C rows 16wv + 4q + r ----
    const int r0 = 16 * wv + 4 * q;
    float wih[4][4], bias[4];
    #pragma unroll
    for (int r = 0; r < 4; ++r) {
        bias[r] = b_ih[r0 + r] + b_hh[r0 + r];
        #pragma unroll
        for (int i = 0; i < ISZ; ++i) wih[r][i] = W_ih[(r0 + r) * ISZ + i];
    }

    // ---- per-lane x pipeline (fp32 from global; quads redundant -> L1 broadcast) ----
    const float* xrow = x + (size_t)(blk0 + n) * SEQ_T * ISZ;
    float4v xcur = *(const float4v*)(xrow);
    float4v xnxt = *(const float4v*)(xrow + ISZ);

    const int gw = 2 * wv + (q >> 1);
    const int j0 = 4 * (q & 1);

    float hl0 = 0.f, hl1 = 0.f, hl2 = 0.f, hl3 = 0.f;

    __syncthreads();   // zero-init visible

#define MFMA16(A, B, C) __builtin_amdgcn_mfma_f32_16x16x32_f16((A), (B), (C), 0, 0, 0)
#define RNN_STEP(RB, WB, T)                                                    \
    {                                                                          \
        int tn = (T) + 2; if (tn > SEQ_T - 1) tn = SEQ_T - 1;                  \
        const float4v xf = *(const float4v*)(xrow + (size_t)tn * ISZ);         \
        half8 B10 = *(const half8*)&hterm[RB][0][    q][n][0];                 \
        half8 B11 = *(const half8*)&hterm[RB][0][4 + q][n][0];                 \
        half8 B20 = *(const half8*)&hterm[RB][1][    q][n][0];                 \
        half8 B21 = *(const half8*)&hterm[RB][1][4 + q][n][0];                 \
        float p0 = bias[0], p1 = bias[1], p2 = bias[2], p3 = bias[3];          \
        _Pragma("unroll")                                                      \
        for (int i = 0; i < ISZ; ++i) {                                        \
            p0 = fmaf(xcur[i], wih[0][i], p0);                                 \
            p1 = fmaf(xcur[i], wih[1][i], p1);                                 \
            p2 = fmaf(xcur[i], wih[2][i], p2);                                 \
            p3 = fmaf(xcur[i], wih[3][i], p3);                                 \
        }                                                                      \
        float4v accA = {p0, p1, p2, p3};                                       \
        float4v accB = {0.f, 0.f, 0.f, 0.f};                                   \
        accA = MFMA16(A10, B10, accA);  accB = MFMA16(A11, B11, accB);         \
        accA = MFMA16(A10, B20, accA);  accB = MFMA16(A11, B21, accB);         \
        accA = MFMA16(A20, B10, accA);  accB = MFMA16(A21, B11, accB);         \
        hl0 = fast_tanh(accA[0] + accB[0]); hl1 = fast_tanh(accA[1] + accB[1]);\
        hl2 = fast_tanh(accA[2] + accB[2]); hl3 = fast_tanh(accA[3] + accB[3]);\
        half2v hi01 = pk_f16(hl0, hl1), hi23 = pk_f16(hl2, hl3);               \
        float s0 = hl0 - (float)hi01[0], s1 = hl1 - (float)hi01[1];            \
        float s2 = hl2 - (float)hi23[0], s3 = hl3 - (float)hi23[1];            \
        half2v lo01 = pk_f16(s0, s1), lo23 = pk_f16(s2, s3);                   \
        uint2v whi = { __builtin_bit_cast(unsigned int, hi01),                 \
                       __builtin_bit_cast(unsigned int, hi23) };               \
        uint2v wlo = { __builtin_bit_cast(unsigned int, lo01),                 \
                       __builtin_bit_cast(unsigned int, lo23) };               \
        *(uint2v*)&hterm[WB][0][gw][n][j0] = whi;                              \
        *(uint2v*)&hterm[WB][1][gw][n][j0] = wlo;                              \
        xcur = xnxt; xnxt = xf;                                                \
        __syncthreads();                                                       \
    }

    for (int t = 0; t < SEQ_T; t += 2) {
        RNN_STEP(0, 1, t)
        RNN_STEP(1, 0, t + 1)
    }
#undef RNN_STEP
#undef MFMA16

    // ---- fc epilogue on fp32 final h (in registers) ----
    {
        float4v hv = {hl0, hl1, hl2, hl3};
        *(float4v*)&hf[n][16 * wv + 4 * q] = hv;
    }
    __syncthreads();
    for (int it = tid; it < RPB * OSZ; it += 256) {
        const int b = it / OSZ;
        const int o = it - b * OSZ;
        const float* wo = fc_W + o * HID;
        float acc = fc_b[o];
        #pragma unroll
        for (int j = 0; j < HID; ++j)
            acc = fmaf(hf[b][j], wo[j], acc);
        out[(size_t)(blk0 + b) * OSZ + o] = acc;
    }
}

extern "C" void kernel_launch(void* const* d_in, const int* in_sizes, int n_in,
                              void* d_out, int out_size, void* d_ws, size_t ws_size,
                              hipStream_t stream) {
    const float* x    = (const float*)d_in[0];
    const float* W_ih = (const float*)d_in[1];
    const float* W_hh = (const float*)d_in[2];
    const float* b_ih = (const float*)d_in[3];
    const float* b_hh = (const float*)d_in[4];
    const float* fc_W = (const float*)d_in[5];
    const float* fc_b = (const float*)d_in[6];
    float* out = (float*)d_out;

    rnn_f16x2_kernel<<<BATCH / RPB, 256, 0, stream>>>(
        x, W_ih, W_hh, b_ih, b_hh, fc_W, fc_b, out);
}